// Round 2
// baseline (12545.211 us; speedup 1.0000x reference)
//
#include <hip/hip_runtime.h>
#include <hip/hip_cooperative_groups.h>
#include <cstddef>

namespace cg = cooperative_groups;

namespace {

constexpr int B  = 128;
constexpr int T  = 256;
constexpr int HD = 512;
constexpr int G  = 2048;   // 4*HD gates
constexpr int TC = 32;     // time chunk for xg buffer
constexpr int XIN = 36;    // 32 real + 4 cat
constexpr int NCHUNK = T / TC;

typedef __attribute__((ext_vector_type(8))) short short8;
typedef __attribute__((ext_vector_type(4))) float f32x4;

__device__ __forceinline__ float sigmf(float x) { return 1.0f / (1.0f + expf(-x)); }
__device__ __forceinline__ float leakyf(float x) { return x >= 0.0f ? x : 0.1f * x; }

__device__ __forceinline__ unsigned short f2bf(float v) {
  union { float f; unsigned u; } x; x.f = v;
  unsigned r = x.u + 0x7fffu + ((x.u >> 16) & 1u);
  return (unsigned short)(r >> 16);
}
__device__ __forceinline__ float bf2f(unsigned short b) {
  union { unsigned u; float f; } x; x.u = ((unsigned)b) << 16; return x.f;
}

// ---------------- prep: Wh (512 x 2048) -> whi/wlo[dir][2048 gatecol][512 k] bf16 hi/lo ----------
__global__ void k_prep_w(const float* __restrict__ Whf, const float* __restrict__ Whr,
                         unsigned short* __restrict__ whi, unsigned short* __restrict__ wlo) {
  __shared__ float tile[32][33];
  const int d = blockIdx.z;
  const float* src = d ? Whr : Whf;
  const int gc0 = blockIdx.x * 32, k0 = blockIdx.y * 32;
  for (int i = threadIdx.y; i < 32; i += 8)
    tile[i][threadIdx.x] = src[(size_t)(k0 + i) * G + gc0 + threadIdx.x];
  __syncthreads();
  for (int i = threadIdx.y; i < 32; i += 8) {
    const float v = tile[threadIdx.x][i];
    const unsigned short h = f2bf(v);
    const unsigned short l = f2bf(v - bf2f(h));
    const size_t o = ((size_t)d * G + gc0 + i) * HD + k0 + threadIdx.x;
    whi[o] = h; wlo[o] = l;
  }
}

// ---------------- K1: embed-gather + GEMM (M=B*T, K=64, N=512) + leaky ----------------
__global__ void k_embed_gemm1(const float* __restrict__ x0, const float* __restrict__ emb,
                              const float* __restrict__ W1, const float* __restrict__ b1,
                              float* __restrict__ x1) {
  __shared__ float As[64][65];
  __shared__ float Bs[64][68];
  const int tid = threadIdx.x;
  const int m0 = blockIdx.x * 64, n0 = blockIdx.y * 64;

  for (int i = tid; i < 64 * 64; i += 256) {
    const int m = i >> 6, k = i & 63;
    const size_t row = (size_t)(m0 + m);
    float v;
    if (k < 32) {
      v = x0[row * XIN + k];
    } else {
      const int c = (k - 32) >> 3, e = (k - 32) & 7;
      const int idx = (int)x0[row * XIN + 32 + c];
      v = emb[(size_t)(c * 100 + idx) * 8 + e];
    }
    As[m][k] = v;
  }
  for (int j = 0; j < 4; ++j) {
    const int q = tid + 256 * j;
    const int kk = q >> 4, nq = q & 15;
    *(float4*)&Bs[kk][nq * 4] = *(const float4*)&W1[(size_t)kk * HD + n0 + nq * 4];
  }
  __syncthreads();

  const int ty = tid >> 4, tx = tid & 15;
  float acc[4][4] = {};
  #pragma unroll 8
  for (int k = 0; k < 64; ++k) {
    const float a0 = As[ty * 4 + 0][k], a1 = As[ty * 4 + 1][k];
    const float a2 = As[ty * 4 + 2][k], a3 = As[ty * 4 + 3][k];
    const float4 bv = *(const float4*)&Bs[k][tx * 4];
    acc[0][0] += a0 * bv.x; acc[0][1] += a0 * bv.y; acc[0][2] += a0 * bv.z; acc[0][3] += a0 * bv.w;
    acc[1][0] += a1 * bv.x; acc[1][1] += a1 * bv.y; acc[1][2] += a1 * bv.z; acc[1][3] += a1 * bv.w;
    acc[2][0] += a2 * bv.x; acc[2][1] += a2 * bv.y; acc[2][2] += a2 * bv.z; acc[2][3] += a2 * bv.w;
    acc[3][0] += a3 * bv.x; acc[3][1] += a3 * bv.y; acc[3][2] += a3 * bv.z; acc[3][3] += a3 * bv.w;
  }
  const float4 b4 = *(const float4*)&b1[n0 + tx * 4];
  for (int i = 0; i < 4; ++i) {
    float4 o;
    o.x = leakyf(acc[i][0] + b4.x);
    o.y = leakyf(acc[i][1] + b4.y);
    o.z = leakyf(acc[i][2] + b4.z);
    o.w = leakyf(acc[i][3] + b4.w);
    *(float4*)&x1[(size_t)(m0 + ty * 4 + i) * HD + n0 + tx * 4] = o;
  }
}

// ---------------- K2: GEMM (M=B*T, K=512, N=512) + leaky ----------------
__global__ void k_gemm2(const float* __restrict__ x1, const float* __restrict__ W2,
                        const float* __restrict__ b2, float* __restrict__ x2) {
  __shared__ float As[128][36];
  __shared__ float Bs[32][68];
  const int tid = threadIdx.x;
  const int m0 = blockIdx.x * 128, n0 = blockIdx.y * 64;
  const int ty = tid >> 4, tx = tid & 15;
  float acc[8][4] = {};

  for (int k0 = 0; k0 < HD; k0 += 32) {
    __syncthreads();
    #pragma unroll
    for (int j = 0; j < 4; ++j) {
      const int q = tid + 256 * j;
      const int m = q >> 3, kq = q & 7;
      *(float4*)&As[m][kq * 4] = *(const float4*)&x1[(size_t)(m0 + m) * HD + k0 + kq * 4];
    }
    #pragma unroll
    for (int j = 0; j < 2; ++j) {
      const int q = tid + 256 * j;
      const int kk = q >> 4, nq = q & 15;
      *(float4*)&Bs[kk][nq * 4] = *(const float4*)&W2[(size_t)(k0 + kk) * HD + n0 + nq * 4];
    }
    __syncthreads();
    #pragma unroll 8
    for (int k = 0; k < 32; ++k) {
      const float4 bv = *(const float4*)&Bs[k][tx * 4];
      #pragma unroll
      for (int i = 0; i < 8; ++i) {
        const float a = As[ty * 8 + i][k];
        acc[i][0] += a * bv.x; acc[i][1] += a * bv.y; acc[i][2] += a * bv.z; acc[i][3] += a * bv.w;
      }
    }
  }
  const float4 b4 = *(const float4*)&b2[n0 + tx * 4];
  for (int i = 0; i < 8; ++i) {
    float4 o;
    o.x = leakyf(acc[i][0] + b4.x);
    o.y = leakyf(acc[i][1] + b4.y);
    o.z = leakyf(acc[i][2] + b4.z);
    o.w = leakyf(acc[i][3] + b4.w);
    *(float4*)&x2[(size_t)(m0 + ty * 8 + i) * HD + n0 + tx * 4] = o;
  }
}

// ---------------- K3: xg chunk GEMM: (TC*B x 512) @ Wi (512x2048) + bi + bh ----------------
__global__ void k_gemm_xg(const float* __restrict__ x2,
                          const float* __restrict__ Wif, const float* __restrict__ Wir,
                          const float* __restrict__ bif, const float* __restrict__ bhf,
                          const float* __restrict__ bir, const float* __restrict__ bhr,
                          float* __restrict__ xg, int c0) {
  __shared__ float As[128][36];
  __shared__ float Bs[32][68];
  const int dir = blockIdx.z;
  const float* Wi = dir ? Wir : Wif;
  const float* bi = dir ? bir : bif;
  const float* bh = dir ? bhr : bhf;
  const int tid = threadIdx.x;
  const int m0 = blockIdx.x * 128, n0 = blockIdx.y * 64;
  const int ty = tid >> 4, tx = tid & 15;
  float acc[8][4] = {};

  for (int k0 = 0; k0 < HD; k0 += 32) {
    __syncthreads();
    #pragma unroll
    for (int j = 0; j < 4; ++j) {
      const int q = tid + 256 * j;
      const int m = q >> 3, kq = q & 7;
      const int r = m0 + m;
      const int b = r & (B - 1);
      const int t = c0 + (r >> 7);
      const int tg = dir ? (T - 1 - t) : t;
      *(float4*)&As[m][kq * 4] = *(const float4*)&x2[((size_t)b * T + tg) * HD + k0 + kq * 4];
    }
    #pragma unroll
    for (int j = 0; j < 2; ++j) {
      const int q = tid + 256 * j;
      const int kk = q >> 4, nq = q & 15;
      *(float4*)&Bs[kk][nq * 4] = *(const float4*)&Wi[(size_t)(k0 + kk) * G + n0 + nq * 4];
    }
    __syncthreads();
    #pragma unroll 8
    for (int k = 0; k < 32; ++k) {
      const float4 bv = *(const float4*)&Bs[k][tx * 4];
      #pragma unroll
      for (int i = 0; i < 8; ++i) {
        const float a = As[ty * 8 + i][k];
        acc[i][0] += a * bv.x; acc[i][1] += a * bv.y; acc[i][2] += a * bv.z; acc[i][3] += a * bv.w;
      }
    }
  }
  const int nb = n0 + tx * 4;
  float4 bias;
  bias.x = bi[nb + 0] + bh[nb + 0];
  bias.y = bi[nb + 1] + bh[nb + 1];
  bias.z = bi[nb + 2] + bh[nb + 2];
  bias.w = bi[nb + 3] + bh[nb + 3];
  for (int i = 0; i < 8; ++i) {
    const int r = m0 + ty * 8 + i;   // = tc*B + b
    float4 o;
    o.x = acc[i][0] + bias.x;
    o.y = acc[i][1] + bias.y;
    o.z = acc[i][2] + bias.z;
    o.w = acc[i][3] + bias.w;
    *(float4*)&xg[((size_t)dir * TC * B + r) * G + nb] = o;
  }
}

// ---------------- K4: cooperative scan over one chunk of TC steps ----------------
// 256 blocks x 512 threads. Block: dir = bid>>7, j0 = (bid&127)*4 (4 hidden units, all 4 gates,
// all 128 batches). Wh frags (bf16 hi/lo) live in REGISTERS for the whole chunk.
// gates tile D[16 cols][128 b] via mfma_f32_16x16x32_bf16, bf16x3 emulation (fp32-class accuracy).
// Wave w computes batch tile w*16..w*16+15. C layout: col(b)=lane&15, row(c)=(lane>>4)*4+reg.
__global__ __launch_bounds__(512) void k_scan_coop(
    const float* __restrict__ xg, const unsigned short* __restrict__ whi,
    const unsigned short* __restrict__ wlo, unsigned short* __restrict__ hhi,
    unsigned short* __restrict__ hlo, float* __restrict__ cbuf,
    float* __restrict__ part, float* __restrict__ out,
    const float* __restrict__ W3, const float* __restrict__ b3, int c0) {
  cg::grid_group grid = cg::this_grid();

  __shared__ float gl[B * 16];     // [b][jl][g]
  __shared__ float ylds[B * 4];    // [b][jl]
  __shared__ float rlds[32][17];

  const int tid  = threadIdx.x;
  const int bid  = blockIdx.x;
  const int dir  = bid >> 7;
  const int j0   = (bid & 127) * 4;
  const int wv   = tid >> 6;       // wave id = batch tile
  const int lane = tid & 63;

  // ---- load weight A-fragments into registers (16 ksteps x hi/lo) ----
  // A-frag lane mapping: row c = lane&15, k = s*32 + (lane>>4)*8 + [0..7]
  const int c16  = lane & 15;
  const int gcol = (c16 >> 2) * HD + j0 + (c16 & 3);
  const size_t woff = ((size_t)dir * G + gcol) * HD + (size_t)((lane >> 4) * 8);
  short8 wh[16], wl[16];
  #pragma unroll
  for (int s = 0; s < 16; ++s) {
    wh[s] = *(const short8*)(whi + woff + s * 32);
    wl[s] = *(const short8*)(wlo + woff + s * 32);
  }

  // ---- per-thread recurrent state: (jl = tid&3, b = tid>>2) ----
  const int jl = tid & 3;
  const int b  = tid >> 2;
  const size_t cidx = ((size_t)dir * B + b) * HD + j0 + jl;
  float creg = (c0 == 0) ? 0.0f : cbuf[cidx];
  const float w3v = W3[dir * HD + j0 + jl];

  for (int tc = 0; tc < TC; ++tc) {
    const int t = c0 + tc;

    // ---- MFMA phase: gates[16 c][128 b] = Wh_slice @ h(t-1)^T ----
    f32x4 acc = {0.0f, 0.0f, 0.0f, 0.0f};
    if (t > 0) {
      const size_t hb = ((size_t)((t & 1) * 2 + dir) * B + (size_t)(wv * 16 + (lane & 15))) * HD
                        + (size_t)((lane >> 4) * 8);
      const unsigned short* ph = hhi + hb;
      const unsigned short* pl = hlo + hb;
      #pragma unroll
      for (int s = 0; s < 16; ++s) {
        const short8 bhv = *(const short8*)(ph + s * 32);
        const short8 blv = *(const short8*)(pl + s * 32);
        acc = __builtin_amdgcn_mfma_f32_16x16x32_bf16(wh[s], bhv, acc, 0, 0, 0);
        acc = __builtin_amdgcn_mfma_f32_16x16x32_bf16(wh[s], blv, acc, 0, 0, 0);
        acc = __builtin_amdgcn_mfma_f32_16x16x32_bf16(wl[s], bhv, acc, 0, 0, 0);
      }
    }
    {
      const int bb = wv * 16 + (lane & 15);
      const int g  = lane >> 4;
      #pragma unroll
      for (int r = 0; r < 4; ++r)
        gl[bb * 16 + r * 4 + g] = acc[r];   // gl[b][jl=r][g]
    }
    __syncthreads();

    // ---- update phase: one (jl, b) per thread ----
    {
      const float* xgrow = xg + (((size_t)dir * TC + tc) * B + b) * G + j0 + jl;
      const f32x4 gv = *(const f32x4*)&gl[b * 16 + jl * 4];
      const float gf = gv.x + xgrow[0];
      const float gi = gv.y + xgrow[HD];
      const float ga = gv.z + xgrow[2 * HD];
      const float go = gv.w + xgrow[3 * HD];
      const float cn = sigmf(gf) * creg + sigmf(gi) * tanhf(ga);
      const float hn = sigmf(go) * tanhf(cn);
      creg = cn;
      const unsigned short hb16 = f2bf(hn);
      const unsigned short lb16 = f2bf(hn - bf2f(hb16));
      const size_t hw = ((size_t)(((t + 1) & 1) * 2 + dir) * B + b) * HD + j0 + jl;
      hhi[hw] = hb16;
      hlo[hw] = lb16;
      ylds[tid] = hn * w3v;   // tid = b*4 + jl
    }
    __syncthreads();

    if (tid < B) {
      const f32x4 yv = *(const f32x4*)&ylds[tid * 4];
      part[((size_t)tc * 256 + bid) * B + tid] = yv.x + yv.y + yv.z + yv.w;
    }
    grid.sync();
  }

  // ---- save c state ----
  cbuf[cidx] = creg;

  // ---- in-kernel y reduction for this chunk: y[b][c0+tc] = b3 + sum over 256 blocks ----
  {
    const int tcr = bid >> 3;
    const int b0r = (bid & 7) * 16;
    const int bb = tid & 15, grp = tid >> 4;
    float ps = 0.0f;
    #pragma unroll
    for (int i = 0; i < 8; ++i)
      ps += part[((size_t)tcr * 256 + grp * 8 + i) * B + b0r + bb];
    rlds[grp][bb] = ps;
    __syncthreads();
    if (tid < 16) {
      float tot = b3[0];
      #pragma unroll
      for (int g2 = 0; g2 < 32; ++g2) tot += rlds[g2][tid];
      out[(size_t)(b0r + tid) * T + c0 + tcr] = tot;
    }
  }
}

}  // namespace

extern "C" void kernel_launch(void* const* d_in, const int* in_sizes, int n_in,
                              void* d_out, int out_size, void* d_ws, size_t ws_size,
                              hipStream_t stream) {
  const float* x0   = (const float*)d_in[0];
  const float* emb  = (const float*)d_in[1];
  const float* W1   = (const float*)d_in[2];
  const float* b1   = (const float*)d_in[3];
  const float* W2   = (const float*)d_in[4];
  const float* b2   = (const float*)d_in[5];
  const float* Wi_f = (const float*)d_in[6];
  const float* bi_f = (const float*)d_in[7];
  const float* Wh_f = (const float*)d_in[8];
  const float* bh_f = (const float*)d_in[9];
  const float* Wi_r = (const float*)d_in[10];
  const float* bi_r = (const float*)d_in[11];
  const float* Wh_r = (const float*)d_in[12];
  const float* bh_r = (const float*)d_in[13];
  const float* W3   = (const float*)d_in[14];
  const float* b3   = (const float*)d_in[15];
  float* out = (float*)d_out;

  // workspace layout (bytes, all 256-aligned): ~141.5 MiB total
  char* wsb = (char*)d_ws;
  float*          bufA = (float*)wsb;                               // 67,108,864 B (x1, then xg)
  float*          x2   = (float*)(wsb + 67108864);                  // 67,108,864 B
  unsigned short* whi  = (unsigned short*)(wsb + 134217728);        //  4,194,304 B
  unsigned short* wlo  = (unsigned short*)(wsb + 138412032);        //  4,194,304 B
  unsigned short* hhi  = (unsigned short*)(wsb + 142606336);        //    524,288 B
  unsigned short* hlo  = (unsigned short*)(wsb + 143130624);        //    524,288 B
  float*          cbuf = (float*)(wsb + 143654912);                 //    524,288 B
  float*          part = (float*)(wsb + 144179200);                 //  4,194,304 B

  k_prep_w<<<dim3(G / 32, HD / 32, 2), dim3(32, 8), 0, stream>>>(Wh_f, Wh_r, whi, wlo);
  k_embed_gemm1<<<dim3(B * T / 64, HD / 64), 256, 0, stream>>>(x0, emb, W1, b1, bufA);
  k_gemm2<<<dim3(B * T / 128, HD / 64), 256, 0, stream>>>(bufA, W2, b2, x2);

  const float* xgc = bufA;
  void* args[11];
  int c0 = 0;
  args[0] = (void*)&xgc;  args[1] = (void*)&whi;  args[2] = (void*)&wlo;
  args[3] = (void*)&hhi;  args[4] = (void*)&hlo;  args[5] = (void*)&cbuf;
  args[6] = (void*)&part; args[7] = (void*)&out;  args[8] = (void*)&W3;
  args[9] = (void*)&b3;   args[10] = (void*)&c0;

  for (int c = 0; c < NCHUNK; ++c) {
    c0 = c * TC;
    k_gemm_xg<<<dim3(TC * B / 128, G / 64, 2), 256, 0, stream>>>(
        x2, Wi_f, Wi_r, bi_f, bh_f, bi_r, bh_r, bufA, c0);
    hipLaunchCooperativeKernel((void*)k_scan_coop, dim3(256), dim3(512), args, 0, stream);
  }
}

// Round 3
// 3590.157 us; speedup vs baseline: 3.4943x; 3.4943x over previous
//
#include <hip/hip_runtime.h>
#include <cstddef>

namespace {

constexpr int B  = 128;
constexpr int T  = 256;
constexpr int HD = 512;
constexpr int G  = 2048;   // 4*HD gates
constexpr int TC = 32;     // time chunk for xg buffer
constexpr int XIN = 36;    // 32 real + 4 cat
constexpr int NCHUNK = T / TC;

typedef __attribute__((ext_vector_type(8))) short short8;
typedef __attribute__((ext_vector_type(4))) short short4v;
typedef __attribute__((ext_vector_type(4))) float f32x4;

__device__ __forceinline__ float sigmf(float x) { return 1.0f / (1.0f + expf(-x)); }
__device__ __forceinline__ float leakyf(float x) { return x >= 0.0f ? x : 0.1f * x; }

__device__ __forceinline__ unsigned short f2bf(float v) {
  union { float f; unsigned u; } x; x.f = v;
  unsigned r = x.u + 0x7fffu + ((x.u >> 16) & 1u);
  return (unsigned short)(r >> 16);
}
__device__ __forceinline__ float bf2f(unsigned short b) {
  union { unsigned u; float f; } x; x.u = ((unsigned)b) << 16; return x.f;
}

// ---------------- prep: transpose [K][N] -> [N][K], split bf16 hi/lo ----------------
__global__ void k_prep(const float* __restrict__ src, unsigned short* __restrict__ dh,
                       unsigned short* __restrict__ dl, int K, int N) {
  __shared__ float tile[32][33];
  const int n0 = blockIdx.x * 32, k0 = blockIdx.y * 32;
  for (int i = threadIdx.y; i < 32; i += 8)
    tile[i][threadIdx.x] = src[(size_t)(k0 + i) * N + n0 + threadIdx.x];
  __syncthreads();
  for (int i = threadIdx.y; i < 32; i += 8) {
    const float v = tile[threadIdx.x][i];
    const unsigned short h = f2bf(v);
    const size_t o = (size_t)(n0 + i) * K + k0 + threadIdx.x;
    dh[o] = h;
    dl[o] = f2bf(v - bf2f(h));
  }
}

__global__ void k_bias(const float* __restrict__ bif, const float* __restrict__ bhf,
                       const float* __restrict__ bir, const float* __restrict__ bhr,
                       float* __restrict__ biasI) {
  const int i = blockIdx.x * 256 + threadIdx.x;   // 4096
  const int d = i >> 11, n = i & 2047;
  biasI[i] = (d ? bir[n] : bif[n]) + (d ? bhr[n] : bhf[n]);
}

// ---------------- K1: embed-gather + GEMM (M=B*T, K=64, N=512) + leaky, out bf16 hi/lo ----------
__global__ void k_embed_gemm1(const float* __restrict__ x0, const float* __restrict__ emb,
                              const float* __restrict__ W1, const float* __restrict__ b1,
                              unsigned short* __restrict__ x1h, unsigned short* __restrict__ x1l) {
  __shared__ float As[64][65];
  __shared__ float Bs[64][68];
  const int tid = threadIdx.x;
  const int m0 = blockIdx.x * 64, n0 = blockIdx.y * 64;

  for (int i = tid; i < 64 * 64; i += 256) {
    const int m = i >> 6, k = i & 63;
    const size_t row = (size_t)(m0 + m);
    float v;
    if (k < 32) {
      v = x0[row * XIN + k];
    } else {
      const int c = (k - 32) >> 3, e = (k - 32) & 7;
      const int idx = (int)x0[row * XIN + 32 + c];
      v = emb[(size_t)(c * 100 + idx) * 8 + e];
    }
    As[m][k] = v;
  }
  for (int j = 0; j < 4; ++j) {
    const int q = tid + 256 * j;
    const int kk = q >> 4, nq = q & 15;
    *(float4*)&Bs[kk][nq * 4] = *(const float4*)&W1[(size_t)kk * HD + n0 + nq * 4];
  }
  __syncthreads();

  const int ty = tid >> 4, tx = tid & 15;
  float acc[4][4] = {};
  #pragma unroll 8
  for (int k = 0; k < 64; ++k) {
    const float a0 = As[ty * 4 + 0][k], a1 = As[ty * 4 + 1][k];
    const float a2 = As[ty * 4 + 2][k], a3 = As[ty * 4 + 3][k];
    const float4 bv = *(const float4*)&Bs[k][tx * 4];
    acc[0][0] += a0 * bv.x; acc[0][1] += a0 * bv.y; acc[0][2] += a0 * bv.z; acc[0][3] += a0 * bv.w;
    acc[1][0] += a1 * bv.x; acc[1][1] += a1 * bv.y; acc[1][2] += a1 * bv.z; acc[1][3] += a1 * bv.w;
    acc[2][0] += a2 * bv.x; acc[2][1] += a2 * bv.y; acc[2][2] += a2 * bv.z; acc[2][3] += a2 * bv.w;
    acc[3][0] += a3 * bv.x; acc[3][1] += a3 * bv.y; acc[3][2] += a3 * bv.z; acc[3][3] += a3 * bv.w;
  }
  const float4 b4 = *(const float4*)&b1[n0 + tx * 4];
  for (int i = 0; i < 4; ++i) {
    float o[4];
    o[0] = leakyf(acc[i][0] + b4.x);
    o[1] = leakyf(acc[i][1] + b4.y);
    o[2] = leakyf(acc[i][2] + b4.z);
    o[3] = leakyf(acc[i][3] + b4.w);
    short4v hv, lv;
    #pragma unroll
    for (int p = 0; p < 4; ++p) {
      const unsigned short hb = f2bf(o[p]);
      hv[p] = (short)hb;
      lv[p] = (short)f2bf(o[p] - bf2f(hb));
    }
    const size_t off = (size_t)(m0 + ty * 4 + i) * HD + n0 + tx * 4;
    *(short4v*)&x1h[off] = hv;
    *(short4v*)&x1l[off] = lv;
  }
}

// ---------------- K2/K3: bf16x3 MFMA GEMM, tile 128x128, BK=32 ----------------
// MODE 0: gemm2  (A=x1 hi/lo, B=W2T, bias=b2, leaky, out bf16 hi/lo, N=512)
// MODE 1: xg     (A=x2 hi/lo gathered rows, B=WiT[dir], bias=biasI[dir], out f32, N=2048)
template <int MODE>
__global__ __launch_bounds__(512) void k_mm(
    const unsigned short* __restrict__ Ah, const unsigned short* __restrict__ Al,
    const unsigned short* __restrict__ Bh, const unsigned short* __restrict__ Bl,
    const float* __restrict__ bias,
    unsigned short* __restrict__ oh, unsigned short* __restrict__ ol,
    float* __restrict__ of, int c0) {
  __shared__ unsigned short As_h[128 * 40], As_l[128 * 40];
  __shared__ unsigned short Bs_h[128 * 40], Bs_l[128 * 40];
  const int tid = threadIdx.x;
  const int m0 = blockIdx.x * 128, n0 = blockIdx.y * 128;
  const int N = MODE ? G : HD;
  const int dir = MODE ? (m0 >> 12) : 0;
  const unsigned short* Bhd = Bh + (size_t)dir * G * HD;
  const unsigned short* Bld = Bl + (size_t)dir * G * HD;

  const int si = tid >> 2, sseg = tid & 3;
  int arow;
  if (MODE) {
    const int r = m0 + si;
    const int tc = (r >> 7) & 31, bb = r & 127;
    const int tg = dir ? (T - 1 - (c0 + tc)) : (c0 + tc);
    arow = bb * T + tg;
  } else {
    arow = m0 + si;
  }
  const int brow = n0 + si;

  const int lane = tid & 63;
  const int c16 = lane & 15, q = lane >> 4;
  const int w = tid >> 6;
  const int mg = w & 3, ng = w >> 2;

  f32x4 acc[2][4] = {};

  for (int k0 = 0; k0 < HD; k0 += 32) {
    __syncthreads();
    *(short8*)&As_h[si * 40 + sseg * 8] = *(const short8*)&Ah[(size_t)arow * HD + k0 + sseg * 8];
    *(short8*)&As_l[si * 40 + sseg * 8] = *(const short8*)&Al[(size_t)arow * HD + k0 + sseg * 8];
    *(short8*)&Bs_h[si * 40 + sseg * 8] = *(const short8*)&Bhd[(size_t)brow * HD + k0 + sseg * 8];
    *(short8*)&Bs_l[si * 40 + sseg * 8] = *(const short8*)&Bld[(size_t)brow * HD + k0 + sseg * 8];
    __syncthreads();

    short8 ah[2], al[2], bh[4], bl[4];
    #pragma unroll
    for (int a = 0; a < 2; ++a) {
      const int rr = (2 * mg + a) * 16 + c16;
      ah[a] = *(const short8*)&As_h[rr * 40 + q * 8];
      al[a] = *(const short8*)&As_l[rr * 40 + q * 8];
    }
    #pragma unroll
    for (int j = 0; j < 4; ++j) {
      const int rr = (4 * ng + j) * 16 + c16;
      bh[j] = *(const short8*)&Bs_h[rr * 40 + q * 8];
      bl[j] = *(const short8*)&Bs_l[rr * 40 + q * 8];
    }
    #pragma unroll
    for (int a = 0; a < 2; ++a)
      #pragma unroll
      for (int j = 0; j < 4; ++j) {
        acc[a][j] = __builtin_amdgcn_mfma_f32_16x16x32_bf16(ah[a], bh[j], acc[a][j], 0, 0, 0);
        acc[a][j] = __builtin_amdgcn_mfma_f32_16x16x32_bf16(ah[a], bl[j], acc[a][j], 0, 0, 0);
        acc[a][j] = __builtin_amdgcn_mfma_f32_16x16x32_bf16(al[a], bh[j], acc[a][j], 0, 0, 0);
      }
  }

  #pragma unroll
  for (int a = 0; a < 2; ++a) {
    #pragma unroll
    for (int j = 0; j < 4; ++j) {
      const int nn = n0 + (4 * ng + j) * 16 + c16;
      const float bv = MODE ? bias[dir * G + nn] : bias[nn];
      #pragma unroll
      for (int r = 0; r < 4; ++r) {
        const int mm = m0 + (2 * mg + a) * 16 + 4 * q + r;
        float v = acc[a][j][r] + bv;
        if (MODE) {
          of[(size_t)mm * G + nn] = v;
        } else {
          v = leakyf(v);
          const unsigned short hb = f2bf(v);
          oh[(size_t)mm * HD + nn] = hb;
          ol[(size_t)mm * HD + nn] = f2bf(v - bf2f(hb));
        }
      }
    }
  }
}

// ---------------- K4: one LSTM step, MFMA bf16x3 ----------------
// grid 128 = dir(2) x jt(16, 32 hidden units) x bt(4, 32 batches). block 512 (8 waves).
// wave w owns gc-tile w (units j0+4w..+3, 4 gates), both 16-batch halves of this block's 32.
__global__ __launch_bounds__(512) void k_step(
    const float* __restrict__ xg, const unsigned short* __restrict__ whi,
    const unsigned short* __restrict__ wlo, unsigned short* __restrict__ hhi,
    unsigned short* __restrict__ hlo, float* __restrict__ cbuf,
    float* __restrict__ part, const float* __restrict__ W3, int t) {
  __shared__ unsigned short hsh[32 * 520];
  __shared__ unsigned short hsl[32 * 520];
  __shared__ float gl_f[32 * 132 + 4];   // [unit][batch*4+gate], u-stride 132
  __shared__ float ysum[32 * 33];

  const int tid = threadIdx.x;
  const int bid = blockIdx.x;
  const int dir = bid >> 6;
  const int jt  = (bid >> 2) & 15;
  const int bt  = bid & 3;
  const int j0  = jt * 32;
  const int b0  = bt * 32;
  const int w    = tid >> 6;
  const int lane = tid & 63;
  const int c16  = lane & 15;
  const int q    = lane >> 4;

  f32x4 acc0 = {0.f, 0.f, 0.f, 0.f};
  f32x4 acc1 = {0.f, 0.f, 0.f, 0.f};

  if (t > 0) {
    // stage h slice (32 b x 512 k, hi+lo) into LDS
    const size_t hb0 = ((size_t)((t & 1) * 2 + dir) * B + b0) * HD;
    #pragma unroll
    for (int i = 0; i < 4; ++i) {
      const int cc = tid + i * 512;
      const int row = cc >> 6, seg = cc & 63;
      *(short8*)&hsh[row * 520 + seg * 8] = *(const short8*)&hhi[hb0 + (size_t)row * HD + seg * 8];
      *(short8*)&hsl[row * 520 + seg * 8] = *(const short8*)&hlo[hb0 + (size_t)row * HD + seg * 8];
    }
    __syncthreads();

    // weight A-frag base: row c16 -> gate=(c16>>2), unit j0+4w+(c16&3)
    const int gcol = (c16 >> 2) * HD + j0 + w * 4 + (c16 & 3);
    const size_t wb = ((size_t)dir * G + gcol) * HD + (size_t)(q * 8);

    #pragma unroll
    for (int ks = 0; ks < 16; ++ks) {
      const short8 wh = *(const short8*)&whi[wb + ks * 32];
      const short8 wl = *(const short8*)&wlo[wb + ks * 32];
      const short8 bh0 = *(const short8*)&hsh[c16 * 520 + ks * 32 + q * 8];
      const short8 bl0 = *(const short8*)&hsl[c16 * 520 + ks * 32 + q * 8];
      const short8 bh1 = *(const short8*)&hsh[(16 + c16) * 520 + ks * 32 + q * 8];
      const short8 bl1 = *(const short8*)&hsl[(16 + c16) * 520 + ks * 32 + q * 8];
      acc0 = __builtin_amdgcn_mfma_f32_16x16x32_bf16(wh, bh0, acc0, 0, 0, 0);
      acc0 = __builtin_amdgcn_mfma_f32_16x16x32_bf16(wh, bl0, acc0, 0, 0, 0);
      acc0 = __builtin_amdgcn_mfma_f32_16x16x32_bf16(wl, bh0, acc0, 0, 0, 0);
      acc1 = __builtin_amdgcn_mfma_f32_16x16x32_bf16(wh, bh1, acc1, 0, 0, 0);
      acc1 = __builtin_amdgcn_mfma_f32_16x16x32_bf16(wh, bl1, acc1, 0, 0, 0);
      acc1 = __builtin_amdgcn_mfma_f32_16x16x32_bf16(wl, bh1, acc1, 0, 0, 0);
    }
    __syncthreads();   // done with hsh/hsl before gl (no overlap, but order anyway)
  }

  // scatter gates to LDS: unit = 4w+r, batch = bt2*16+c16, gate = q
  #pragma unroll
  for (int r = 0; r < 4; ++r) {
    gl_f[(4 * w + r) * 132 + c16 * 4 + q] = acc0[r];
    gl_f[(4 * w + r) * 132 + (16 + c16) * 4 + q] = acc1[r];
  }
  __syncthreads();

  // update: thread -> (b_l = tid>>4, units u2 and u2+16)
  {
    const int b_l = tid >> 4, u2 = tid & 15;
    const int bg = b0 + b_l;
    const int tc = t & (TC - 1);
    const float* xr0 = xg + (((size_t)dir * TC + tc) * B + bg) * G;
    float ysub = 0.0f;
    #pragma unroll
    for (int p = 0; p < 2; ++p) {
      const int ul = u2 + p * 16;
      const int jg = j0 + ul;
      const float* g4 = &gl_f[ul * 132 + b_l * 4];
      const float gf = g4[0] + xr0[jg];
      const float gi = g4[1] + xr0[HD + jg];
      const float ga = g4[2] + xr0[2 * HD + jg];
      const float go = g4[3] + xr0[3 * HD + jg];
      const size_t ci = ((size_t)dir * B + bg) * HD + jg;
      const float co = (t == 0) ? 0.0f : cbuf[ci];
      const float cn = sigmf(gf) * co + sigmf(gi) * tanhf(ga);
      const float hn = sigmf(go) * tanhf(cn);
      cbuf[ci] = cn;
      const unsigned short hb = f2bf(hn);
      const size_t hw = ((size_t)(((t + 1) & 1) * 2 + dir) * B + bg) * HD + jg;
      hhi[hw] = hb;
      hlo[hw] = f2bf(hn - bf2f(hb));
      ysub += hn * W3[dir * HD + jg];
    }
    ysum[b_l * 33 + u2] = ysub;
  }
  __syncthreads();

  if (tid < 32) {
    float s = 0.0f;
    #pragma unroll
    for (int i = 0; i < 16; ++i) s += ysum[tid * 33 + i];
    part[((size_t)t * 32 + dir * 16 + jt) * B + b0 + tid] = s;
  }
}

// ---------------- K5: final reduce: out[b][t] = b3 + sum_g part[t][g][b] ----------------
__global__ void k_out(const float* __restrict__ part, const float* __restrict__ b3,
                      float* __restrict__ out) {
  const int o = blockIdx.x * 256 + threadIdx.x;  // 32768
  const int b = o & 127, t = o >> 7;
  float s = b3[0];
  #pragma unroll
  for (int g = 0; g < 32; ++g) s += part[((size_t)t * 32 + g) * B + b];
  out[(size_t)b * T + t] = s;
}

}  // namespace

extern "C" void kernel_launch(void* const* d_in, const int* in_sizes, int n_in,
                              void* d_out, int out_size, void* d_ws, size_t ws_size,
                              hipStream_t stream) {
  const float* x0   = (const float*)d_in[0];
  const float* emb  = (const float*)d_in[1];
  const float* W1   = (const float*)d_in[2];
  const float* b1   = (const float*)d_in[3];
  const float* W2   = (const float*)d_in[4];
  const float* b2   = (const float*)d_in[5];
  const float* Wi_f = (const float*)d_in[6];
  const float* bi_f = (const float*)d_in[7];
  const float* Wh_f = (const float*)d_in[8];
  const float* bh_f = (const float*)d_in[9];
  const float* Wi_r = (const float*)d_in[10];
  const float* bi_r = (const float*)d_in[11];
  const float* Wh_r = (const float*)d_in[12];
  const float* bh_r = (const float*)d_in[13];
  const float* W3   = (const float*)d_in[14];
  const float* b3   = (const float*)d_in[15];
  float* out = (float*)d_out;

  // workspace layout (bytes), total ~150.5 MiB
  char* wsb = (char*)d_ws;
  unsigned short* x1h  = (unsigned short*)(wsb + 0);           // 33,554,432 (bufA, reused as xg)
  unsigned short* x1l  = (unsigned short*)(wsb + 33554432);    // 33,554,432
  float*          xgf  = (float*)(wsb + 0);                    // 67,108,864 (chunk xg, after gemm2)
  unsigned short* x2h  = (unsigned short*)(wsb + 67108864);    // 33,554,432
  unsigned short* x2l  = (unsigned short*)(wsb + 100663296);   // 33,554,432
  unsigned short* whi  = (unsigned short*)(wsb + 134217728);   //  4,194,304
  unsigned short* wlo  = (unsigned short*)(wsb + 138412032);   //  4,194,304
  unsigned short* wih  = (unsigned short*)(wsb + 142606336);   //  4,194,304
  unsigned short* wil  = (unsigned short*)(wsb + 146800640);   //  4,194,304
  unsigned short* w2h  = (unsigned short*)(wsb + 150994944);   //    524,288
  unsigned short* w2l  = (unsigned short*)(wsb + 151519232);   //    524,288
  unsigned short* hhi  = (unsigned short*)(wsb + 152043520);   //    524,288
  unsigned short* hlo  = (unsigned short*)(wsb + 152567808);   //    524,288
  float*          cbuf = (float*)(wsb + 153092096);            //    524,288
  float*          part = (float*)(wsb + 153616384);            //  4,194,304
  float*          bia  = (float*)(wsb + 157810688);            //     16,384

  // prep: transpose+split weights
  k_prep<<<dim3(G / 32, HD / 32), dim3(32, 8), 0, stream>>>(Wh_f, whi, wlo, HD, G);
  k_prep<<<dim3(G / 32, HD / 32), dim3(32, 8), 0, stream>>>(Wh_r, whi + (size_t)G * HD, wlo + (size_t)G * HD, HD, G);
  k_prep<<<dim3(G / 32, HD / 32), dim3(32, 8), 0, stream>>>(Wi_f, wih, wil, HD, G);
  k_prep<<<dim3(G / 32, HD / 32), dim3(32, 8), 0, stream>>>(Wi_r, wih + (size_t)G * HD, wil + (size_t)G * HD, HD, G);
  k_prep<<<dim3(HD / 32, HD / 32), dim3(32, 8), 0, stream>>>(W2, w2h, w2l, HD, HD);
  k_bias<<<dim3(16), 256, 0, stream>>>(bi_f, bh_f, bi_r, bh_r, bia);

  // x1 = leaky(embed @ W1 + b1), bf16 hi/lo
  k_embed_gemm1<<<dim3(B * T / 64, HD / 64), 256, 0, stream>>>(x0, emb, W1, b1, x1h, x1l);

  // x2 = leaky(x1 @ W2 + b2), bf16 hi/lo (MFMA bf16x3)
  k_mm<0><<<dim3(B * T / 128, HD / 128), 512, 0, stream>>>(
      x1h, x1l, w2h, w2l, b2, x2h, x2l, nullptr, 0);

  for (int c = 0; c < NCHUNK; ++c) {
    const int c0 = c * TC;
    // xg chunk = x2(gathered rows) @ Wi + bi + bh  (MFMA bf16x3)
    k_mm<1><<<dim3(2 * TC * B / 128, G / 128), 512, 0, stream>>>(
        x2h, x2l, wih, wil, bia, nullptr, nullptr, xgf, c0);
    for (int tt = 0; tt < TC; ++tt)
      k_step<<<dim3(128), 512, 0, stream>>>(xgf, whi, wlo, hhi, hlo, cbuf, part, W3, c0 + tt);
  }

  k_out<<<dim3(B * T / 256), 256, 0, stream>>>(part, b3, out);
}